// Round 1
// baseline (521.573 us; speedup 1.0000x reference)
//
#include <hip/hip_runtime.h>

namespace {
constexpr int kN = 50000;
constexpr int kD = 256;
constexpr int kPos = 32;
constexpr int kNeg = 20;
constexpr float kEps = 1e-15f;

// One wave per row. Wave = 4 groups x 16 lanes; each group handles one
// neighbor per iteration; lane t of a group covers elements {j*64 + t*4 .. +3}
// so each global_load_dwordx4 fetches 4 x 256B contiguous segments.
__global__ __launch_bounds__(256) void row_loss_kernel(
    const float* __restrict__ emb,
    const int* __restrict__ nbr,
    const int* __restrict__ nbrm,
    const int* __restrict__ neg,
    const int* __restrict__ rmask,
    float* __restrict__ acc)  // acc[0]=numerator, acc[1]=denominator
{
    __shared__ float s_num[4];
    __shared__ float s_den[4];
    const int wave = threadIdx.x >> 6;
    const int lane = threadIdx.x & 63;
    const int n = blockIdx.x * 4 + wave;   // kN % 4 == 0, always in range
    const int g = lane >> 4;               // neighbor slot within iteration
    const int t = lane & 15;               // element chunk within group

    const float4* erow = reinterpret_cast<const float4*>(emb + (size_t)n * kD);
    float4 own4[4];
#pragma unroll
    for (int j = 0; j < 4; ++j) own4[j] = erow[j * 16 + t];

    float pos_sum = 0.f, neg_sum = 0.f, cnt = 0.f;

    const int* nrow = nbr + (size_t)n * kPos;
    const int* mrow = nbrm + (size_t)n * kPos;
#pragma unroll
    for (int it = 0; it < kPos / 4; ++it) {
        const int idx = nrow[it * 4 + g];
        const int m = mrow[it * 4 + g];
        const float4* brow = reinterpret_cast<const float4*>(emb + (size_t)idx * kD);
        float d = 0.f;
#pragma unroll
        for (int j = 0; j < 4; ++j) {
            const float4 b = brow[j * 16 + t];
            const float4 a = own4[j];
            d += a.x * b.x + a.y * b.y + a.z * b.z + a.w * b.w;
        }
        d += __shfl_xor(d, 8);
        d += __shfl_xor(d, 4);
        d += __shfl_xor(d, 2);
        d += __shfl_xor(d, 1);
        // all 16 lanes of the group now hold the dot
        const float s = 1.f / (1.f + __expf(-d));
        const float term = -__logf(s + kEps);
        const float mf = (float)m;
        pos_sum += term * mf;
        cnt += mf;
    }

    const int* grow = neg + (size_t)n * kNeg;
#pragma unroll
    for (int it = 0; it < kNeg / 4; ++it) {
        const int idx = grow[it * 4 + g];
        const float4* brow = reinterpret_cast<const float4*>(emb + (size_t)idx * kD);
        float d = 0.f;
#pragma unroll
        for (int j = 0; j < 4; ++j) {
            const float4 b = brow[j * 16 + t];
            const float4 a = own4[j];
            d += a.x * b.x + a.y * b.y + a.z * b.z + a.w * b.w;
        }
        d += __shfl_xor(d, 8);
        d += __shfl_xor(d, 4);
        d += __shfl_xor(d, 2);
        d += __shfl_xor(d, 1);
        const float s = 1.f / (1.f + __expf(-d));
        const float term = -__logf(1.f - s + kEps);
        neg_sum += term;
    }

    // combine the 4 groups (every lane in a group holds identical values)
    pos_sum += __shfl_xor(pos_sum, 16);
    pos_sum += __shfl_xor(pos_sum, 32);
    neg_sum += __shfl_xor(neg_sum, 16);
    neg_sum += __shfl_xor(neg_sum, 32);
    cnt += __shfl_xor(cnt, 16);
    cnt += __shfl_xor(cnt, 32);

    if (lane == 0) {
        float row = 0.f;
        if (cnt > 0.f) {  // cnt==0 -> NaN row in reference -> contributes 0
            row = pos_sum / cnt + neg_sum / (float)kNeg;
        }
        const float rm = (float)rmask[n];
        s_num[wave] = row * rm;
        s_den[wave] = rm;
    }
    __syncthreads();
    if (threadIdx.x == 0) {
        atomicAdd(&acc[0], s_num[0] + s_num[1] + s_num[2] + s_num[3]);
        atomicAdd(&acc[1], s_den[0] + s_den[1] + s_den[2] + s_den[3]);
    }
}

__global__ void finalize_kernel(const float* __restrict__ acc,
                                float* __restrict__ out) {
    out[0] = acc[0] / acc[1];
}
}  // namespace

extern "C" void kernel_launch(void* const* d_in, const int* in_sizes, int n_in,
                              void* d_out, int out_size, void* d_ws, size_t ws_size,
                              hipStream_t stream) {
    const float* emb = (const float*)d_in[0];
    const int* nbr = (const int*)d_in[1];
    const int* nbrm = (const int*)d_in[2];
    const int* neg = (const int*)d_in[3];
    const int* rmask = (const int*)d_in[4];
    float* acc = (float*)d_ws;

    hipMemsetAsync(acc, 0, 2 * sizeof(float), stream);
    row_loss_kernel<<<kN / 4, 256, 0, stream>>>(emb, nbr, nbrm, neg, rmask, acc);
    finalize_kernel<<<1, 1, 0, stream>>>(acc, (float*)d_out);
}

// Round 2
// 429.994 us; speedup vs baseline: 1.2130x; 1.2130x over previous
//
#include <hip/hip_runtime.h>
#include <hip/hip_bf16.h>

namespace {
constexpr int kN = 50000;
constexpr int kD = 256;
constexpr int kPos = 32;
constexpr int kNeg = 20;
constexpr float kEps = 1e-15f;

// ---------- fp32 -> bf16 table conversion (runs every launch; d_ws is re-poisoned) ----------
__global__ __launch_bounds__(256) void convert_kernel(const float* __restrict__ emb,
                                                      ushort* __restrict__ tbl) {
    const size_t i = ((size_t)blockIdx.x * 256 + threadIdx.x) * 8;  // 8 floats/thread
    const float4* src = reinterpret_cast<const float4*>(emb + i);
    const float4 a = src[0];
    const float4 b = src[1];
    __hip_bfloat16 h[8];
    h[0] = __float2bfloat16(a.x); h[1] = __float2bfloat16(a.y);
    h[2] = __float2bfloat16(a.z); h[3] = __float2bfloat16(a.w);
    h[4] = __float2bfloat16(b.x); h[5] = __float2bfloat16(b.y);
    h[6] = __float2bfloat16(b.z); h[7] = __float2bfloat16(b.w);
    *reinterpret_cast<uint4*>(tbl + i) = *reinterpret_cast<const uint4*>(h);
}

__device__ __forceinline__ float bf16_dot_pair(unsigned u, float e0, float e1, float d) {
    d = fmaf(__uint_as_float(u << 16), e0, d);
    d = fmaf(__uint_as_float(u & 0xffff0000u), e1, d);
    return d;
}

// One wave per row; wave = 4 groups x 16 lanes, one neighbor per group per iter.
// bf16 row = 512 B; lane t loads uint4 chunks {t, 16+t} so each load instruction
// covers 256 B contiguous (4 full cache lines).
__global__ __launch_bounds__(256) void row_loss_bf16(
    const float* __restrict__ emb,
    const ushort* __restrict__ tbl,
    const int* __restrict__ nbr,
    const int* __restrict__ nbrm,
    const int* __restrict__ neg,
    const int* __restrict__ rmask,
    float* __restrict__ acc) {
    __shared__ float s_num[4];
    __shared__ float s_den[4];
    const int wave = threadIdx.x >> 6;
    const int lane = threadIdx.x & 63;
    const int n = blockIdx.x * 4 + wave;
    const int g = lane >> 4;
    const int t = lane & 15;

    const int rm = rmask[n];
    float num = 0.f;

    if (rm) {
        const float4* erow = reinterpret_cast<const float4*>(emb + (size_t)n * kD);
        // own elements matching lane t's bf16 chunks: elems [8t..8t+7] and [128+8t..128+8t+7]
        const float4 f0 = erow[2 * t];
        const float4 f1 = erow[2 * t + 1];
        const float4 f2 = erow[32 + 2 * t];
        const float4 f3 = erow[33 + 2 * t];
        const float own[16] = {f0.x, f0.y, f0.z, f0.w, f1.x, f1.y, f1.z, f1.w,
                               f2.x, f2.y, f2.z, f2.w, f3.x, f3.y, f3.z, f3.w};

        const int* nrow = nbr + (size_t)n * kPos;
        const int* mrow = nbrm + (size_t)n * kPos;
        const int* grow = neg + (size_t)n * kNeg;

        int pidx[kPos / 4], pm[kPos / 4], gidx[kNeg / 4];
#pragma unroll
        for (int it = 0; it < kPos / 4; ++it) {
            pidx[it] = nrow[it * 4 + g];
            pm[it] = mrow[it * 4 + g];
        }
#pragma unroll
        for (int it = 0; it < kNeg / 4; ++it) gidx[it] = grow[it * 4 + g];

        float pos_sum = 0.f, neg_sum = 0.f, cnt = 0.f;

#pragma unroll
        for (int it = 0; it < kPos / 4; ++it) {
            cnt += (float)pm[it];
            if (pm[it]) {  // group-uniform: skip load + dot entirely when masked
                const uint4* rp = reinterpret_cast<const uint4*>(tbl + (size_t)pidx[it] * kD);
                const uint4 u0 = rp[t];
                const uint4 u1 = rp[16 + t];
                float d = 0.f;
                d = bf16_dot_pair(u0.x, own[0], own[1], d);
                d = bf16_dot_pair(u0.y, own[2], own[3], d);
                d = bf16_dot_pair(u0.z, own[4], own[5], d);
                d = bf16_dot_pair(u0.w, own[6], own[7], d);
                d = bf16_dot_pair(u1.x, own[8], own[9], d);
                d = bf16_dot_pair(u1.y, own[10], own[11], d);
                d = bf16_dot_pair(u1.z, own[12], own[13], d);
                d = bf16_dot_pair(u1.w, own[14], own[15], d);
                d += __shfl_xor(d, 8);
                d += __shfl_xor(d, 4);
                d += __shfl_xor(d, 2);
                d += __shfl_xor(d, 1);
                const float s = 1.f / (1.f + __expf(-d));
                pos_sum += -__logf(s + kEps);
            }
        }

#pragma unroll
        for (int it = 0; it < kNeg / 4; ++it) {
            const uint4* rp = reinterpret_cast<const uint4*>(tbl + (size_t)gidx[it] * kD);
            const uint4 u0 = rp[t];
            const uint4 u1 = rp[16 + t];
            float d = 0.f;
            d = bf16_dot_pair(u0.x, own[0], own[1], d);
            d = bf16_dot_pair(u0.y, own[2], own[3], d);
            d = bf16_dot_pair(u0.z, own[4], own[5], d);
            d = bf16_dot_pair(u0.w, own[6], own[7], d);
            d = bf16_dot_pair(u1.x, own[8], own[9], d);
            d = bf16_dot_pair(u1.y, own[10], own[11], d);
            d = bf16_dot_pair(u1.z, own[12], own[13], d);
            d = bf16_dot_pair(u1.w, own[14], own[15], d);
            d += __shfl_xor(d, 8);
            d += __shfl_xor(d, 4);
            d += __shfl_xor(d, 2);
            d += __shfl_xor(d, 1);
            const float s = 1.f / (1.f + __expf(-d));
            neg_sum += -__logf(1.f - s + kEps);
        }

        // combine the 4 groups
        pos_sum += __shfl_xor(pos_sum, 16);
        pos_sum += __shfl_xor(pos_sum, 32);
        neg_sum += __shfl_xor(neg_sum, 16);
        neg_sum += __shfl_xor(neg_sum, 32);
        cnt += __shfl_xor(cnt, 16);
        cnt += __shfl_xor(cnt, 32);

        if (cnt > 0.f) num = pos_sum / cnt + neg_sum / (float)kNeg;
        // cnt==0 -> NaN row in reference -> replaced by 0 -> contributes 0
    }

    if (lane == 0) {
        s_num[wave] = num;
        s_den[wave] = (float)rm;
    }
    __syncthreads();
    if (threadIdx.x == 0) {
        atomicAdd(&acc[0], s_num[0] + s_num[1] + s_num[2] + s_num[3]);
        atomicAdd(&acc[1], s_den[0] + s_den[1] + s_den[2] + s_den[3]);
    }
}

// ---------- fp32 fallback (if d_ws can't hold the bf16 table) ----------
__global__ __launch_bounds__(256) void row_loss_f32(
    const float* __restrict__ emb,
    const int* __restrict__ nbr,
    const int* __restrict__ nbrm,
    const int* __restrict__ neg,
    const int* __restrict__ rmask,
    float* __restrict__ acc) {
    __shared__ float s_num[4];
    __shared__ float s_den[4];
    const int wave = threadIdx.x >> 6;
    const int lane = threadIdx.x & 63;
    const int n = blockIdx.x * 4 + wave;
    const int g = lane >> 4;
    const int t = lane & 15;

    const int rm = rmask[n];
    float num = 0.f;

    if (rm) {
        const float4* erow = reinterpret_cast<const float4*>(emb + (size_t)n * kD);
        float4 own4[4];
#pragma unroll
        for (int j = 0; j < 4; ++j) own4[j] = erow[j * 16 + t];

        const int* nrow = nbr + (size_t)n * kPos;
        const int* mrow = nbrm + (size_t)n * kPos;
        const int* grow = neg + (size_t)n * kNeg;

        float pos_sum = 0.f, neg_sum = 0.f, cnt = 0.f;

#pragma unroll
        for (int it = 0; it < kPos / 4; ++it) {
            const int idx = nrow[it * 4 + g];
            const int m = mrow[it * 4 + g];
            cnt += (float)m;
            if (m) {
                const float4* brow = reinterpret_cast<const float4*>(emb + (size_t)idx * kD);
                float d = 0.f;
#pragma unroll
                for (int j = 0; j < 4; ++j) {
                    const float4 b = brow[j * 16 + t];
                    const float4 a = own4[j];
                    d += a.x * b.x + a.y * b.y + a.z * b.z + a.w * b.w;
                }
                d += __shfl_xor(d, 8);
                d += __shfl_xor(d, 4);
                d += __shfl_xor(d, 2);
                d += __shfl_xor(d, 1);
                const float s = 1.f / (1.f + __expf(-d));
                pos_sum += -__logf(s + kEps);
            }
        }

#pragma unroll
        for (int it = 0; it < kNeg / 4; ++it) {
            const int idx = grow[it * 4 + g];
            const float4* brow = reinterpret_cast<const float4*>(emb + (size_t)idx * kD);
            float d = 0.f;
#pragma unroll
            for (int j = 0; j < 4; ++j) {
                const float4 b = brow[j * 16 + t];
                const float4 a = own4[j];
                d += a.x * b.x + a.y * b.y + a.z * b.z + a.w * b.w;
            }
            d += __shfl_xor(d, 8);
            d += __shfl_xor(d, 4);
            d += __shfl_xor(d, 2);
            d += __shfl_xor(d, 1);
            const float s = 1.f / (1.f + __expf(-d));
            neg_sum += -__logf(1.f - s + kEps);
        }

        pos_sum += __shfl_xor(pos_sum, 16);
        pos_sum += __shfl_xor(pos_sum, 32);
        neg_sum += __shfl_xor(neg_sum, 16);
        neg_sum += __shfl_xor(neg_sum, 32);
        cnt += __shfl_xor(cnt, 16);
        cnt += __shfl_xor(cnt, 32);

        if (cnt > 0.f) num = pos_sum / cnt + neg_sum / (float)kNeg;
    }

    if (lane == 0) {
        s_num[wave] = num;
        s_den[wave] = (float)rm;
    }
    __syncthreads();
    if (threadIdx.x == 0) {
        atomicAdd(&acc[0], s_num[0] + s_num[1] + s_num[2] + s_num[3]);
        atomicAdd(&acc[1], s_den[0] + s_den[1] + s_den[2] + s_den[3]);
    }
}

__global__ void finalize_kernel(const float* __restrict__ acc, float* __restrict__ out) {
    out[0] = acc[0] / acc[1];
}
}  // namespace

extern "C" void kernel_launch(void* const* d_in, const int* in_sizes, int n_in,
                              void* d_out, int out_size, void* d_ws, size_t ws_size,
                              hipStream_t stream) {
    const float* emb = (const float*)d_in[0];
    const int* nbr = (const int*)d_in[1];
    const int* nbrm = (const int*)d_in[2];
    const int* neg = (const int*)d_in[3];
    const int* rmask = (const int*)d_in[4];
    float* acc = (float*)d_ws;

    hipMemsetAsync(acc, 0, 2 * sizeof(float), stream);

    const size_t tbl_bytes = (size_t)kN * kD * sizeof(ushort);
    if (ws_size >= 256 + tbl_bytes) {
        ushort* tbl = (ushort*)((char*)d_ws + 256);
        convert_kernel<<<(kN * kD / 8 + 255) / 256, 256, 0, stream>>>(emb, tbl);
        row_loss_bf16<<<kN / 4, 256, 0, stream>>>(emb, tbl, nbr, nbrm, neg, rmask, acc);
    } else {
        row_loss_f32<<<kN / 4, 256, 0, stream>>>(emb, nbr, nbrm, neg, rmask, acc);
    }
    finalize_kernel<<<1, 1, 0, stream>>>(acc, (float*)d_out);
}